// Round 11
// baseline (133.975 us; speedup 1.0000x reference)
//
#include <hip/hip_runtime.h>

#define BB 4
#define TT 2048
#define EE 256
#define HH 8
#define DD 32
#define JOINED 25
// (1/sqrt(32)) * log2(e) — folded into Q at qkv time; softmax done in exp2 domain
#define CSCALE 0.2550539239731586f

typedef __attribute__((ext_vector_type(8))) __bf16 bf16x8;
typedef __attribute__((ext_vector_type(4))) float f32x4;

// float -> bf16 round-to-nearest-even
static __device__ __forceinline__ unsigned short f2bf(float f) {
    unsigned u = __float_as_uint(f);
    u += 0x7fffu + ((u >> 16) & 1u);
    return (unsigned short)(u >> 16);
}
// packed pair (two RNE converts + pack)
static __device__ __forceinline__ unsigned pk2bf(float a, float b) {
    return (unsigned)f2bf(a) | ((unsigned)f2bf(b) << 16);
}
// convert 8 consecutive fp32 -> packed uint4 of 8 bf16
static __device__ __forceinline__ uint4 cvt8(const float* p) {
    float4 a = *(const float4*)p;
    float4 b = *(const float4*)(p + 4);
    uint4 o;
    o.x = pk2bf(a.x, a.y); o.y = pk2bf(a.z, a.w);
    o.z = pk2bf(b.x, b.y); o.w = pk2bf(b.z, b.w);
    return o;
}

union BF8U { uint4 u; bf16x8 b; };
static __device__ __forceinline__ bf16x8 ld_frag(const unsigned short* p) {
    BF8U t; t.u = *(const uint4*)p; return t.b;
}

#define MFMA(a, b, c) __builtin_amdgcn_mfma_f32_16x16x32_bf16((a), (b), (c), 0, 0, 0)

// ---------------------------------------------------------------------------
// Kernel 1: fused QKV projection — 128x128 block tile, 64x64 per wave,
// 4x4 accumulators, BK=128. Reads fp32 X and the selected fp32 weight matrix
// DIRECTLY (inline fp32->bf16 conversion during LDS staging; slabs re-read
// from L2/L3). which = blockIdx.y>>1 (block-uniform), n-half = blockIdx.y&1.
//  Q -> (b,h,t,d) pre-scaled by CSCALE; K -> (b,h,t,d);
//  V -> (b,h,d,t) transposed with masked t (t%25==24) zeroed.
// ---------------------------------------------------------------------------
__global__ __launch_bounds__(256) void qkv_kernel(
    const float* __restrict__ x,
    const float* __restrict__ Wq, const float* __restrict__ Wk,
    const float* __restrict__ Wv,
    const float* __restrict__ bq, const float* __restrict__ bk,
    const float* __restrict__ bv,
    unsigned short* __restrict__ qo, unsigned short* __restrict__ ko,
    unsigned short* __restrict__ vto)
{
    __shared__ unsigned short As[128*136];
    __shared__ unsigned short Bs[128*136];

    const int m0 = blockIdx.x * 128;
    const int which = blockIdx.y >> 1;        // 0=Q 1=K 2=V (block-uniform)
    const int n0 = (blockIdx.y & 1) * 128;    // n within the selected matrix
    const float* __restrict__ W    = which == 0 ? Wq : which == 1 ? Wk : Wv;
    const float* __restrict__ bias = which == 0 ? bq : which == 1 ? bk : bv;

    const int tid = threadIdx.x;
    const int w = tid >> 6, lane = tid & 63, quad = lane >> 4, lq = lane & 15;
    const int wm = (w & 1) * 64, wn = (w >> 1) * 64;
    const int srow = tid >> 4, scol = (tid & 15) * 8;

    f32x4 acc[4][4] = {};

    for (int k0 = 0; k0 < EE; k0 += 128) {
        __syncthreads();
        #pragma unroll
        for (int i = 0; i < 8; ++i) {
            int r = i * 16 + srow;
            *(uint4*)&As[r*136 + scol] = cvt8(&x[(size_t)(m0 + r)*EE + k0 + scol]);
            *(uint4*)&Bs[r*136 + scol] = cvt8(&W[(size_t)(n0 + r)*EE + k0 + scol]);
        }
        __syncthreads();
        #pragma unroll
        for (int ks = 0; ks < 4; ++ks) {
            bf16x8 af[4], bfr[4];
            #pragma unroll
            for (int t = 0; t < 4; ++t) {
                af[t]  = ld_frag(&As[(wm + t*16 + lq)*136 + ks*32 + quad*8]);
                bfr[t] = ld_frag(&Bs[(wn + t*16 + lq)*136 + ks*32 + quad*8]);
            }
            #pragma unroll
            for (int mi = 0; mi < 4; ++mi)
                #pragma unroll
                for (int f = 0; f < 4; ++f)
                    acc[mi][f] = MFMA(af[mi], bfr[f], acc[mi][f]);
        }
    }

    #pragma unroll
    for (int f = 0; f < 4; ++f) {
        int nf = n0 + wn + f*16 + lq;            // feature within the matrix
        int h = nf >> 5, d = nf & 31;
        float bb = bias[nf];
        #pragma unroll
        for (int mi = 0; mi < 4; ++mi) {
            int t0 = m0 + wm + mi*16 + quad*4;   // first of 4 consecutive t
            int b = t0 >> 11, tl = t0 & (TT - 1);
            if (which == 0) {
                #pragma unroll
                for (int reg = 0; reg < 4; ++reg)
                    qo[(((size_t)b*HH + h)*TT + tl + reg)*DD + d] =
                        f2bf((acc[mi][f][reg] + bb) * CSCALE);
            } else if (which == 1) {
                #pragma unroll
                for (int reg = 0; reg < 4; ++reg)
                    ko[(((size_t)b*HH + h)*TT + tl + reg)*DD + d] =
                        f2bf(acc[mi][f][reg] + bb);
            } else {
                int r25 = tl % JOINED;
                int mreg = (JOINED - 1) - r25;   // masked reg if in [0,3]
                float vv[4];
                #pragma unroll
                for (int reg = 0; reg < 4; ++reg)
                    vv[reg] = (reg == mreg) ? 0.f : (acc[mi][f][reg] + bb);
                uint2 pk;
                pk.x = pk2bf(vv[0], vv[1]);
                pk.y = pk2bf(vv[2], vv[3]);
                *(uint2*)&vto[(((size_t)b*HH + h)*DD + d)*TT + tl] = pk;
            }
        }
    }
}

// ---------------------------------------------------------------------------
// Kernel 2: flash attention — EXACT round-7 structure (best measured):
// 4 waves / 64 Q rows per block, K/V double-buffered in LDS, one barrier per
// KV iteration, XCD swizzle, fixed-max exp2 softmax, MFMA denominator vs
// masked-ones table (LDS, built per block), V columns pre-zeroed.
// ---------------------------------------------------------------------------
__global__ __launch_bounds__(256, 4) void attn_kernel(
    const unsigned short* __restrict__ q, const unsigned short* __restrict__ k,
    const unsigned short* __restrict__ vt, unsigned short* __restrict__ ao)
{
    __shared__ unsigned short Ks[2][64*40];  // [kv][d], pad 40 shorts/row
    __shared__ unsigned short Vt[2][32*72];  // [d][kv], pad 72 shorts/row
    __shared__ unsigned short Ps[4][16*72];  // per-wave P
    __shared__ unsigned short onesTab[JOINED*64];

    const int L = blockIdx.x;                // 0..1023
    const int xcd   = L & 7;
    const int inner = L >> 3;                // 0..127
    const int bh = xcd * 4 + (inner & 3);    // 4 bh per XCD group
    const int iq = 31 - (inner >> 2);        // heavy tiles first
    const int b = bh >> 3, hh = bh & 7;

    const int tid = threadIdx.x;
    const int w = tid >> 6, lane = tid & 63, quad = lane >> 4, lq = lane & 15;
    const int r0 = iq * 64;
    const int q0 = r0 + w*16;
    const int ntiles = iq + 1;

    const int rk = tid >> 2, ck = (tid & 3) * 8;   // K: 64 rows x 32 d
    const int rv = tid >> 3, cv = (tid & 7) * 8;   // V^T: 32 rows(d) x 64 kv

    // masked-ones table (before the first barrier)
    for (int i = tid; i < JOINED*64; i += 256) {
        int phase = i >> 6, o = i & 63;
        onesTab[i] = (((phase + o) % JOINED) != (JOINED - 1)) ? (unsigned short)0x3F80
                                                              : (unsigned short)0;
    }

    const unsigned short* qb_ = q  + (size_t)bh * TT * DD;
    const unsigned short* kb_ = k  + (size_t)bh * TT * DD;
    const unsigned short* vb_ = vt + (size_t)bh * DD * TT;

    const bf16x8 qf = ld_frag(qb_ + (size_t)(q0 + lq)*DD + quad*8);

    // preload tile 0
    {
        uint4 kreg = *(const uint4*)(kb_ + (size_t)rk*DD + ck);
        uint4 vreg = *(const uint4*)(vb_ + (size_t)rv*TT + cv);
        *(uint4*)&Ks[0][rk*40 + ck] = kreg;
        *(uint4*)&Vt[0][rv*72 + cv] = vreg;
    }
    __syncthreads();

    f32x4 O0 = {0,0,0,0}, O1 = {0,0,0,0}, Ld = {0,0,0,0};
    int phase = 0;

    for (int jt = 0; jt < ntiles; ++jt) {
        const int j0 = jt * 64;
        // 1. prefetch next tile into registers (clamped dummy on last iter)
        const int jn = (jt + 1 < ntiles) ? j0 + 64 : j0;
        uint4 kreg = *(const uint4*)(kb_ + (size_t)(jn + rk)*DD + ck);
        uint4 vreg = *(const uint4*)(vb_ + (size_t)rv*TT + jn + cv);

        bf16x8 ones0 = ld_frag(&onesTab[phase*64 +      quad*8]);
        bf16x8 ones1 = ld_frag(&onesTab[phase*64 + 32 + quad*8]);

        // 2. compute on LDS buffer jt&1
        const unsigned short* Kb = &Ks[jt & 1][0];
        const unsigned short* Vb = &Vt[jt & 1][0];

        f32x4 St[4];
        #pragma unroll
        for (int f = 0; f < 4; ++f) {
            bf16x8 kf = ld_frag(&Kb[(f*16 + lq)*40 + quad*8]);
            f32x4 z = {0,0,0,0};
            St[f] = MFMA(kf, qf, z);
        }
        if (jt == ntiles - 1) {   // diagonal tile: causal mask
            int row = q0 + lq;
            #pragma unroll
            for (int f = 0; f < 4; ++f) {
                int kvb = j0 + f*16 + quad*4;
                #pragma unroll
                for (int reg = 0; reg < 4; ++reg)
                    St[f][reg] = (kvb + reg <= row) ? St[f][reg] : -1e30f;
            }
        }
        // p = exp2(s), pack, per-wave LDS write
        unsigned short* ps = &Ps[w][0];
        #pragma unroll
        for (int f = 0; f < 4; ++f) {
            float p0 = __builtin_amdgcn_exp2f(St[f][0]);
            float p1 = __builtin_amdgcn_exp2f(St[f][1]);
            float p2 = __builtin_amdgcn_exp2f(St[f][2]);
            float p3 = __builtin_amdgcn_exp2f(St[f][3]);
            uint2 pk;
            pk.x = pk2bf(p0, p1);
            pk.y = pk2bf(p2, p3);
            *(uint2*)&ps[lq*72 + f*16 + quad*4] = pk;
        }
        // PV + denominator
        #pragma unroll
        for (int c = 0; c < 2; ++c) {
            bf16x8 pa  = ld_frag(&ps[lq*72 + c*32 + quad*8]);
            bf16x8 v0f = ld_frag(&Vb[(lq)*72      + c*32 + quad*8]);   // d 0..15
            bf16x8 v1f = ld_frag(&Vb[(16 + lq)*72 + c*32 + quad*8]);   // d 16..31
            O0 = MFMA(pa, v0f, O0);
            O1 = MFMA(pa, v1f, O1);
            Ld = MFMA(pa, (c ? ones1 : ones0), Ld);
        }

        // 3. write prefetched tile to the other buffer, single barrier
        *(uint4*)&Ks[(jt + 1) & 1][rk*40 + ck] = kreg;
        *(uint4*)&Vt[(jt + 1) & 1][rv*72 + cv] = vreg;
        __syncthreads();

        phase += 14; if (phase >= JOINED) phase -= JOINED;   // (j0+64) mod 25
    }

    // epilogue: O/l -> ao (b,t,E) bf16
    #pragma unroll
    for (int reg = 0; reg < 4; ++reg) {
        float inv = 1.0f / Ld[reg];
        int t = q0 + quad*4 + reg;
        size_t ob = ((size_t)b*TT + t)*EE + hh*DD;
        ao[ob + lq]      = f2bf(O0[reg] * inv);
        ao[ob + 16 + lq] = f2bf(O1[reg] * inv);
    }
}

// ---------------------------------------------------------------------------
// Kernel 3: output projection — 128x128 / 4x4-acc structure. Reads bf16 ao
// and fp32 Wo (inline conversion during staging). fp32 out + bias.
// ---------------------------------------------------------------------------
__global__ __launch_bounds__(256) void proj_kernel(
    const unsigned short* __restrict__ a, const float* __restrict__ W,
    const float* __restrict__ bias, float* __restrict__ out)
{
    __shared__ unsigned short As[128*136];
    __shared__ unsigned short Bs[128*136];

    const int m0 = blockIdx.x * 128;
    const int n0 = blockIdx.y * 128;
    const int tid = threadIdx.x;
    const int w = tid >> 6, lane = tid & 63, quad = lane >> 4, lq = lane & 15;
    const int wm = (w & 1) * 64, wn = (w >> 1) * 64;
    const int srow = tid >> 4, scol = (tid & 15) * 8;

    f32x4 acc[4][4] = {};

    for (int k0 = 0; k0 < EE; k0 += 128) {
        __syncthreads();
        #pragma unroll
        for (int i = 0; i < 8; ++i) {
            int r = i * 16 + srow;
            *(uint4*)&As[r*136 + scol] = *(const uint4*)&a[(size_t)(m0 + r)*EE + k0 + scol];
            *(uint4*)&Bs[r*136 + scol] = cvt8(&W[(size_t)(n0 + r)*EE + k0 + scol]);
        }
        __syncthreads();
        #pragma unroll
        for (int ks = 0; ks < 4; ++ks) {
            bf16x8 af[4], bfr[4];
            #pragma unroll
            for (int t = 0; t < 4; ++t) {
                af[t]  = ld_frag(&As[(wm + t*16 + lq)*136 + ks*32 + quad*8]);
                bfr[t] = ld_frag(&Bs[(wn + t*16 + lq)*136 + ks*32 + quad*8]);
            }
            #pragma unroll
            for (int mi = 0; mi < 4; ++mi)
                #pragma unroll
                for (int f = 0; f < 4; ++f)
                    acc[mi][f] = MFMA(af[mi], bfr[f], acc[mi][f]);
        }
    }

    #pragma unroll
    for (int f = 0; f < 4; ++f) {
        int n = n0 + wn + f*16 + lq;
        float bb = bias[n];
        #pragma unroll
        for (int mi = 0; mi < 4; ++mi) {
            int m = m0 + wm + mi*16 + quad*4;
            #pragma unroll
            for (int reg = 0; reg < 4; ++reg)
                out[(size_t)(m + reg)*EE + n] = acc[mi][f][reg] + bb;
        }
    }
}

extern "C" void kernel_launch(void* const* d_in, const int* in_sizes, int n_in,
                              void* d_out, int out_size, void* d_ws, size_t ws_size,
                              hipStream_t stream) {
    const float* x  = (const float*)d_in[0];
    const float* Wq = (const float*)d_in[1];
    const float* bq = (const float*)d_in[2];
    const float* Wk = (const float*)d_in[3];
    const float* bk = (const float*)d_in[4];
    const float* Wv = (const float*)d_in[5];
    const float* bv = (const float*)d_in[6];
    const float* Wo = (const float*)d_in[7];
    const float* bo = (const float*)d_in[8];
    float* out = (float*)d_out;

    const size_t n_elem = (size_t)BB * TT * EE;       // 2,097,152
    unsigned short* qq  = (unsigned short*)d_ws;
    unsigned short* kk  = qq  + n_elem;
    unsigned short* vtt = kk  + n_elem;
    unsigned short* ao  = vtt + n_elem;

    qkv_kernel <<<dim3(BB*TT/128, 6), 256, 0, stream>>>(
        x, Wq, Wk, Wv, bq, bk, bv, qq, kk, vtt);
    attn_kernel<<<dim3(1024), 256, 0, stream>>>(qq, kk, vtt, ao);
    proj_kernel<<<dim3(BB*TT/128, EE/128), 256, 0, stream>>>(ao, Wo, bo, out);
}

// Round 12
// 119.833 us; speedup vs baseline: 1.1180x; 1.1180x over previous
//
#include <hip/hip_runtime.h>

#define BB 4
#define TT 2048
#define EE 256
#define HH 8
#define DD 32
#define JOINED 25
// (1/sqrt(32)) * log2(e) — folded into Q at qkv time; softmax done in exp2 domain
#define CSCALE 0.2550539239731586f

typedef __attribute__((ext_vector_type(8))) __bf16 bf16x8;
typedef __attribute__((ext_vector_type(4))) float f32x4;

// float -> bf16 round-to-nearest-even
static __device__ __forceinline__ unsigned short f2bf(float f) {
    unsigned u = __float_as_uint(f);
    u += 0x7fffu + ((u >> 16) & 1u);
    return (unsigned short)(u >> 16);
}
// packed pair (two RNE converts + pack)
static __device__ __forceinline__ unsigned pk2bf(float a, float b) {
    return (unsigned)f2bf(a) | ((unsigned)f2bf(b) << 16);
}

union BF8U { uint4 u; bf16x8 b; };
static __device__ __forceinline__ bf16x8 ld_frag(const unsigned short* p) {
    BF8U t; t.u = *(const uint4*)p; return t.b;
}

#define MFMA(a, b, c) __builtin_amdgcn_mfma_f32_16x16x32_bf16((a), (b), (c), 0, 0, 0)

// ---------------------------------------------------------------------------
// Kernel 0: prep — fp32 -> bf16 for X and the 4 weight matrices, plus the
// 25-phase masked-ones table (bf16 1.0 where (phase+o)%25 != 24) in global.
// ---------------------------------------------------------------------------
__global__ __launch_bounds__(256) void prep_kernel(
    const float* __restrict__ x,
    const float* __restrict__ Wq, const float* __restrict__ Wk,
    const float* __restrict__ Wv, const float* __restrict__ Wo,
    unsigned short* __restrict__ xb, unsigned short* __restrict__ wqb,
    unsigned short* __restrict__ wkb, unsigned short* __restrict__ wvb,
    unsigned short* __restrict__ wob, unsigned short* __restrict__ onesG)
{
    const size_t NX = (size_t)BB * TT * EE;
    const size_t NMAIN = NX + 4 * (size_t)EE * EE;
    size_t idx = ((size_t)blockIdx.x * 256 + threadIdx.x) * 8;
    if (idx >= NMAIN) {
        size_t base = idx - NMAIN;
        #pragma unroll
        for (int i = 0; i < 8; ++i) {
            size_t e = base + i;
            if (e < (size_t)JOINED * 64) {
                int phase = (int)(e >> 6), o = (int)(e & 63);
                onesG[e] = (((phase + o) % JOINED) != (JOINED - 1)) ? (unsigned short)0x3F80
                                                                    : (unsigned short)0;
            }
        }
        return;
    }
    const float* src; unsigned short* dst; size_t off;
    if (idx < NX) { src = x; dst = xb; off = idx; }
    else {
        size_t i2 = idx - NX;
        int wsel = (int)(i2 >> 16);
        off = i2 & 65535u;
        src = wsel == 0 ? Wq : wsel == 1 ? Wk : wsel == 2 ? Wv : Wo;
        dst = wsel == 0 ? wqb : wsel == 1 ? wkb : wsel == 2 ? wvb : wob;
    }
    float4 a = *(const float4*)(src + off);
    float4 b = *(const float4*)(src + off + 4);
    uint4 o;
    o.x = pk2bf(a.x, a.y); o.y = pk2bf(a.z, a.w);
    o.z = pk2bf(b.x, b.y); o.w = pk2bf(b.z, b.w);
    *(uint4*)(dst + off) = o;
}

// ---------------------------------------------------------------------------
// Kernel 1: fused QKV projection (NT GEMM, bf16, fp32 accum, BK=64).
//  Q -> (b,h,t,d) pre-scaled by CSCALE; K -> (b,h,t,d);
//  V -> (b,h,d,t) transposed with masked t (t%25==24) zeroed.
// ---------------------------------------------------------------------------
__global__ __launch_bounds__(256) void qkv_kernel(
    const unsigned short* __restrict__ xb,
    const unsigned short* __restrict__ wq, const float* __restrict__ bq,
    const unsigned short* __restrict__ wk, const float* __restrict__ bk,
    const unsigned short* __restrict__ wv, const float* __restrict__ bv,
    unsigned short* __restrict__ qo, unsigned short* __restrict__ ko,
    unsigned short* __restrict__ vto)
{
    __shared__ unsigned short Xs[64*72];   // 64 m-rows x 64 k, pad 72
    __shared__ unsigned short Ws[64*72];

    const int m0 = blockIdx.x * 64;
    const int nb = blockIdx.y;             // 0..11
    const int which = nb >> 2;             // 0=Q 1=K 2=V
    const int n0 = (nb & 3) * 64;
    const unsigned short* __restrict__ W = which == 0 ? wq : which == 1 ? wk : wv;
    const float* __restrict__ bias       = which == 0 ? bq : which == 1 ? bk : bv;

    const int tid = threadIdx.x;
    const int w = tid >> 6, lane = tid & 63, quad = lane >> 4, lq = lane & 15;
    const int sr = tid >> 2, sc = (tid & 3) * 16;

    f32x4 acc[4] = {{0,0,0,0},{0,0,0,0},{0,0,0,0},{0,0,0,0}};

    for (int k0 = 0; k0 < EE; k0 += 64) {
        __syncthreads();
        *(uint4*)&Xs[sr*72 + sc]     = *(const uint4*)&xb[(size_t)(m0 + sr)*EE + k0 + sc];
        *(uint4*)&Xs[sr*72 + sc + 8] = *(const uint4*)&xb[(size_t)(m0 + sr)*EE + k0 + sc + 8];
        *(uint4*)&Ws[sr*72 + sc]     = *(const uint4*)&W [(size_t)(n0 + sr)*EE + k0 + sc];
        *(uint4*)&Ws[sr*72 + sc + 8] = *(const uint4*)&W [(size_t)(n0 + sr)*EE + k0 + sc + 8];
        __syncthreads();
        bf16x8 a0 = ld_frag(&Xs[(w*16 + lq)*72 + quad*8]);
        bf16x8 a1 = ld_frag(&Xs[(w*16 + lq)*72 + 32 + quad*8]);
        #pragma unroll
        for (int f = 0; f < 4; ++f) {
            bf16x8 b0 = ld_frag(&Ws[(f*16 + lq)*72 + quad*8]);
            bf16x8 b1 = ld_frag(&Ws[(f*16 + lq)*72 + 32 + quad*8]);
            acc[f] = MFMA(a0, b0, acc[f]);
            acc[f] = MFMA(a1, b1, acc[f]);
        }
    }

    const int t0 = (m0 + w*16 + quad*4);       // first of 4 consecutive t (rows)
    const int b  = t0 >> 11;
    const int tl = t0 & (TT - 1);

    #pragma unroll
    for (int f = 0; f < 4; ++f) {
        int n = n0 + f*16 + lq;                // output feature
        int h = n >> 5, d = n & 31;
        float bb = bias[n];
        if (which == 0) {
            #pragma unroll
            for (int reg = 0; reg < 4; ++reg)
                qo[(((size_t)b*HH + h)*TT + tl + reg)*DD + d] = f2bf((acc[f][reg] + bb) * CSCALE);
        } else if (which == 1) {
            #pragma unroll
            for (int reg = 0; reg < 4; ++reg)
                ko[(((size_t)b*HH + h)*TT + tl + reg)*DD + d] = f2bf(acc[f][reg] + bb);
        } else {
            // V transposed, masked t zeroed, packed b64 store (4 consecutive t)
            int r25 = tl % JOINED;
            int mreg = (JOINED - 1) - r25;     // reg index that is masked, if in [0,3]
            float vv[4];
            #pragma unroll
            for (int reg = 0; reg < 4; ++reg)
                vv[reg] = (reg == mreg) ? 0.f : (acc[f][reg] + bb);
            uint2 pk;
            pk.x = pk2bf(vv[0], vv[1]);
            pk.y = pk2bf(vv[2], vv[3]);
            *(uint2*)&vto[(((size_t)b*HH + h)*DD + d)*TT + tl] = pk;
        }
    }
}

// ---------------------------------------------------------------------------
// Kernel 2: flash attention — measured-best (r7) structure:
// 4 waves / 64 Q rows per block, K/V tiles double-buffered in LDS (shared by
// all 4 waves), ONE barrier per KV iteration:
//   [prefetch next tile -> regs] [compute from LDS buf A] [regs -> buf B]
//   [barrier]
// XCD swizzle: blockIdx.x & 7 -> 4-bh group per XCD; K/V hot set ~1 MB < L2.
// Fixed-max softmax (exact: scores O(1)); denominator via MFMA vs masked-ones
// from global (L2 broadcast); V columns pre-zeroed at t%25==24.
// ---------------------------------------------------------------------------
__global__ __launch_bounds__(256, 4) void attn_kernel(
    const unsigned short* __restrict__ q, const unsigned short* __restrict__ k,
    const unsigned short* __restrict__ vt, const unsigned short* __restrict__ onesG,
    unsigned short* __restrict__ ao)
{
    __shared__ unsigned short Ks[2][64*40];  // [kv][d], pad 40 shorts/row
    __shared__ unsigned short Vt[2][32*72];  // [d][kv], pad 72 shorts/row
    __shared__ unsigned short Ps[4][16*72];  // per-wave P

    const int L = blockIdx.x;                // 0..1023
    const int xcd   = L & 7;
    const int inner = L >> 3;                // 0..127
    const int bh = xcd * 4 + (inner & 3);    // 4 bh per XCD group
    const int iq = 31 - (inner >> 2);        // heavy tiles first
    const int b = bh >> 3, hh = bh & 7;

    const int tid = threadIdx.x;
    const int w = tid >> 6, lane = tid & 63, quad = lane >> 4, lq = lane & 15;
    const int r0 = iq * 64;
    const int q0 = r0 + w*16;
    const int ntiles = iq + 1;

    const int rk = tid >> 2, ck = (tid & 3) * 8;   // K: 64 rows x 32 d
    const int rv = tid >> 3, cv = (tid & 7) * 8;   // V^T: 32 rows(d) x 64 kv

    const unsigned short* qb_ = q  + (size_t)bh * TT * DD;
    const unsigned short* kb_ = k  + (size_t)bh * TT * DD;
    const unsigned short* vb_ = vt + (size_t)bh * DD * TT;

    const bf16x8 qf = ld_frag(qb_ + (size_t)(q0 + lq)*DD + quad*8);

    // preload tile 0
    {
        uint4 kreg = *(const uint4*)(kb_ + (size_t)rk*DD + ck);
        uint4 vreg = *(const uint4*)(vb_ + (size_t)rv*TT + cv);
        *(uint4*)&Ks[0][rk*40 + ck] = kreg;
        *(uint4*)&Vt[0][rv*72 + cv] = vreg;
    }
    __syncthreads();

    f32x4 O0 = {0,0,0,0}, O1 = {0,0,0,0}, Ld = {0,0,0,0};
    int phase = 0;

    for (int jt = 0; jt < ntiles; ++jt) {
        const int j0 = jt * 64;
        // 1. prefetch next tile into registers (clamped dummy on last iter)
        const int jn = (jt + 1 < ntiles) ? j0 + 64 : j0;
        uint4 kreg = *(const uint4*)(kb_ + (size_t)(jn + rk)*DD + ck);
        uint4 vreg = *(const uint4*)(vb_ + (size_t)rv*TT + jn + cv);

        bf16x8 ones0 = ld_frag(&onesG[phase*64 +      quad*8]);
        bf16x8 ones1 = ld_frag(&onesG[phase*64 + 32 + quad*8]);

        // 2. compute on LDS buffer jt&1
        const unsigned short* Kb = &Ks[jt & 1][0];
        const unsigned short* Vb = &Vt[jt & 1][0];

        f32x4 St[4];
        #pragma unroll
        for (int f = 0; f < 4; ++f) {
            bf16x8 kf = ld_frag(&Kb[(f*16 + lq)*40 + quad*8]);
            f32x4 z = {0,0,0,0};
            St[f] = MFMA(kf, qf, z);
        }
        if (jt == ntiles - 1) {   // diagonal tile: causal mask
            int row = q0 + lq;
            #pragma unroll
            for (int f = 0; f < 4; ++f) {
                int kvb = j0 + f*16 + quad*4;
                #pragma unroll
                for (int reg = 0; reg < 4; ++reg)
                    St[f][reg] = (kvb + reg <= row) ? St[f][reg] : -1e30f;
            }
        }
        // p = exp2(s), pack, per-wave LDS write
        unsigned short* ps = &Ps[w][0];
        #pragma unroll
        for (int f = 0; f < 4; ++f) {
            float p0 = __builtin_amdgcn_exp2f(St[f][0]);
            float p1 = __builtin_amdgcn_exp2f(St[f][1]);
            float p2 = __builtin_amdgcn_exp2f(St[f][2]);
            float p3 = __builtin_amdgcn_exp2f(St[f][3]);
            uint2 pk;
            pk.x = pk2bf(p0, p1);
            pk.y = pk2bf(p2, p3);
            *(uint2*)&ps[lq*72 + f*16 + quad*4] = pk;
        }
        // PV + denominator
        #pragma unroll
        for (int c = 0; c < 2; ++c) {
            bf16x8 pa  = ld_frag(&ps[lq*72 + c*32 + quad*8]);
            bf16x8 v0f = ld_frag(&Vb[(lq)*72      + c*32 + quad*8]);   // d 0..15
            bf16x8 v1f = ld_frag(&Vb[(16 + lq)*72 + c*32 + quad*8]);   // d 16..31
            O0 = MFMA(pa, v0f, O0);
            O1 = MFMA(pa, v1f, O1);
            Ld = MFMA(pa, (c ? ones1 : ones0), Ld);
        }

        // 3. write prefetched tile to the other buffer, single barrier
        *(uint4*)&Ks[(jt + 1) & 1][rk*40 + ck] = kreg;
        *(uint4*)&Vt[(jt + 1) & 1][rv*72 + cv] = vreg;
        __syncthreads();

        phase += 14; if (phase >= JOINED) phase -= JOINED;   // (j0+64) mod 25
    }

    // epilogue: O/l -> ao (b,t,E) bf16
    #pragma unroll
    for (int reg = 0; reg < 4; ++reg) {
        float inv = 1.0f / Ld[reg];
        int t = q0 + quad*4 + reg;
        size_t ob = ((size_t)b*TT + t)*EE + hh*DD;
        ao[ob + lq]      = f2bf(O0[reg] * inv);
        ao[ob + 16 + lq] = f2bf(O1[reg] * inv);
    }
}

// ---------------------------------------------------------------------------
// Kernel 3: output projection (bf16 NT GEMM, BK=64, fp32 out + bias).
// ---------------------------------------------------------------------------
__global__ __launch_bounds__(256) void proj_kernel(
    const unsigned short* __restrict__ a, const unsigned short* __restrict__ W,
    const float* __restrict__ bias, float* __restrict__ out)
{
    __shared__ unsigned short Xs[64*72];
    __shared__ unsigned short Ws[64*72];

    const int m0 = blockIdx.x * 64;
    const int n0 = blockIdx.y * 64;
    const int tid = threadIdx.x;
    const int w = tid >> 6, lane = tid & 63, quad = lane >> 4, lq = lane & 15;
    const int sr = tid >> 2, sc = (tid & 3) * 16;

    f32x4 acc[4] = {{0,0,0,0},{0,0,0,0},{0,0,0,0},{0,0,0,0}};

    for (int k0 = 0; k0 < EE; k0 += 64) {
        __syncthreads();
        *(uint4*)&Xs[sr*72 + sc]     = *(const uint4*)&a[(size_t)(m0 + sr)*EE + k0 + sc];
        *(uint4*)&Xs[sr*72 + sc + 8] = *(const uint4*)&a[(size_t)(m0 + sr)*EE + k0 + sc + 8];
        *(uint4*)&Ws[sr*72 + sc]     = *(const uint4*)&W[(size_t)(n0 + sr)*EE + k0 + sc];
        *(uint4*)&Ws[sr*72 + sc + 8] = *(const uint4*)&W[(size_t)(n0 + sr)*EE + k0 + sc + 8];
        __syncthreads();
        bf16x8 a0 = ld_frag(&Xs[(w*16 + lq)*72 + quad*8]);
        bf16x8 a1 = ld_frag(&Xs[(w*16 + lq)*72 + 32 + quad*8]);
        #pragma unroll
        for (int f = 0; f < 4; ++f) {
            bf16x8 b0 = ld_frag(&Ws[(f*16 + lq)*72 + quad*8]);
            bf16x8 b1 = ld_frag(&Ws[(f*16 + lq)*72 + 32 + quad*8]);
            acc[f] = MFMA(a0, b0, acc[f]);
            acc[f] = MFMA(a1, b1, acc[f]);
        }
    }

    #pragma unroll
    for (int f = 0; f < 4; ++f) {
        int n = n0 + f*16 + lq;
        float bb = bias[n];
        #pragma unroll
        for (int reg = 0; reg < 4; ++reg) {
            int m = m0 + w*16 + quad*4 + reg;
            out[(size_t)m*EE + n] = acc[f][reg] + bb;
        }
    }
}

extern "C" void kernel_launch(void* const* d_in, const int* in_sizes, int n_in,
                              void* d_out, int out_size, void* d_ws, size_t ws_size,
                              hipStream_t stream) {
    const float* x  = (const float*)d_in[0];
    const float* Wq = (const float*)d_in[1];
    const float* bq = (const float*)d_in[2];
    const float* Wk = (const float*)d_in[3];
    const float* bk = (const float*)d_in[4];
    const float* Wv = (const float*)d_in[5];
    const float* bv = (const float*)d_in[6];
    const float* Wo = (const float*)d_in[7];
    const float* bo = (const float*)d_in[8];
    float* out = (float*)d_out;

    const size_t n_elem = (size_t)BB * TT * EE;       // 2,097,152
    const size_t w_elem = (size_t)EE * EE;            // 65,536
    unsigned short* xb    = (unsigned short*)d_ws;
    unsigned short* wqb   = xb  + n_elem;
    unsigned short* wkb   = wqb + w_elem;
    unsigned short* wvb   = wkb + w_elem;
    unsigned short* wob   = wvb + w_elem;
    unsigned short* qq    = wob + w_elem;
    unsigned short* kk    = qq  + n_elem;
    unsigned short* vtt   = kk  + n_elem;
    unsigned short* ao    = vtt + n_elem;
    unsigned short* onesG = ao  + n_elem;

    const int prep_blocks = (int)((n_elem + 4*w_elem) / 2048) + 1;  // +1: ones table
    prep_kernel<<<dim3(prep_blocks), 256, 0, stream>>>(
        x, Wq, Wk, Wv, Wo, xb, wqb, wkb, wvb, wob, onesG);
    qkv_kernel <<<dim3(BB*TT/64, 12), 256, 0, stream>>>(
        xb, wqb, bq, wkb, bk, wvb, bv, qq, kk, vtt);
    attn_kernel<<<dim3(1024), 256, 0, stream>>>(qq, kk, vtt, onesG, ao);
    proj_kernel<<<dim3(BB*TT/64, EE/64), 256, 0, stream>>>(ao, wob, bo, out);
}